// Round 4
// baseline (2680.571 us; speedup 1.0000x reference)
//
#include <hip/hip_runtime.h>

typedef short s8v __attribute__((ext_vector_type(8)));
typedef float f32x4 __attribute__((ext_vector_type(4)));

#define OBS_T 8
#define NSTEPS 20

__device__ __forceinline__ unsigned short f2bf(float x) {
    unsigned u = __float_as_uint(x);
    u = (u + 0x7FFFu + ((u >> 16) & 1u)) >> 16;
    return (unsigned short)u;
}
__device__ __forceinline__ float bf2f(unsigned short h) {
    return __uint_as_float(((unsigned)h) << 16);
}

// 6-product bf16x3 accumulate: (H+M+L)x(H'+M'+L') keeping HH,HM,MH,HL,LH,MM
// ordered small->large to minimize f32 accumulation rounding.
__device__ __forceinline__ f32x4 mfma6(s8v ah, s8v am, s8v al,
                                       s8v bh, s8v bm, s8v bl, f32x4 acc) {
    acc = __builtin_amdgcn_mfma_f32_16x16x32_bf16(al, bh, acc, 0, 0, 0);
    acc = __builtin_amdgcn_mfma_f32_16x16x32_bf16(ah, bl, acc, 0, 0, 0);
    acc = __builtin_amdgcn_mfma_f32_16x16x32_bf16(am, bm, acc, 0, 0, 0);
    acc = __builtin_amdgcn_mfma_f32_16x16x32_bf16(am, bh, acc, 0, 0, 0);
    acc = __builtin_amdgcn_mfma_f32_16x16x32_bf16(ah, bm, acc, 0, 0, 0);
    acc = __builtin_amdgcn_mfma_f32_16x16x32_bf16(ah, bh, acc, 0, 0, 0);
    return acc;
}

__device__ __forceinline__ void store3(unsigned short* H, unsigned short* M,
                                       unsigned short* L, int ci, float v) {
    unsigned short h = f2bf(v);
    float r1 = v - bf2f(h);
    unsigned short m = f2bf(r1);
    H[ci] = h; M[ci] = m; L[ci] = f2bf(r1 - bf2f(m));
}

// ---------------- prep: pack 3-way-split bf16 weight fragments ----------------
// W4frag: [nt(32)][kstep(8)][lane(64)][j(8)]  n = nt*16+(l&15), k = ks*32+(l>>4)*8+j
// Wpfrag: [bin(64)][nt(4)][kstep(4)][lane(64)][j(8)] e = nt*16+(l&15), k = ks*32+(l>>4)*8+j
__global__ void slstm_prep(const float* __restrict__ Wp,
                           const float* __restrict__ Wi, const float* __restrict__ Wf,
                           const float* __restrict__ Wo, const float* __restrict__ Wg,
                           unsigned short* __restrict__ W4H, unsigned short* __restrict__ W4M,
                           unsigned short* __restrict__ W4L,
                           unsigned short* __restrict__ WpH, unsigned short* __restrict__ WpM,
                           unsigned short* __restrict__ WpL) {
    int x = blockIdx.x * blockDim.x + threadIdx.x;
    const int NW4 = 32 * 8 * 64 * 8;      // 131072
    const int NWP = 64 * 4 * 4 * 64 * 8;  // 524288
    if (x < NW4) {
        int j = x & 7, lane = (x >> 3) & 63, ks = (x >> 9) & 7, nt = x >> 12;
        int n = nt * 16 + (lane & 15);
        int k = ks * 32 + ((lane >> 4) << 3) + j;
        int gt = n >> 7, col = n & 127;
        const float* W = (gt == 0) ? Wi : (gt == 1) ? Wf : (gt == 2) ? Wo : Wg;
        float v = W[k * 128 + col];
        unsigned short h = f2bf(v);
        float r1 = v - bf2f(h);
        unsigned short m = f2bf(r1);
        W4H[x] = h; W4M[x] = m; W4L[x] = f2bf(r1 - bf2f(m));
    } else if (x < NW4 + NWP) {
        int y = x - NW4;
        int j = y & 7, lane = (y >> 3) & 63, ks = (y >> 9) & 3, nt = (y >> 11) & 3, bin = y >> 13;
        int e = nt * 16 + (lane & 15);
        int k = ks * 32 + ((lane >> 4) << 3) + j;
        float v = Wp[(bin * 128 + k) * 64 + e];
        unsigned short h = f2bf(v);
        float r1 = v - bf2f(h);
        unsigned short m = f2bf(r1);
        WpH[y] = h; WpM[y] = m; WpL[y] = f2bf(r1 - bf2f(m));
    }
}

// ---------------- main persistent kernel: 1 WG per sequence ----------------
__global__ __launch_bounds__(512, 2) void slstm_main(
    const float* __restrict__ obs_rel, const float* __restrict__ obs_abs,
    const float* __restrict__ We, const float* __restrict__ be,
    const float* __restrict__ bp,
    const float* __restrict__ bi, const float* __restrict__ bfv,
    const float* __restrict__ bo, const float* __restrict__ bg,
    const float* __restrict__ Wout, const float* __restrict__ bout,
    const unsigned short* __restrict__ W4H, const unsigned short* __restrict__ W4M,
    const unsigned short* __restrict__ W4L,
    const unsigned short* __restrict__ WpH, const unsigned short* __restrict__ WpM,
    const unsigned short* __restrict__ WpL,
    float* __restrict__ out) {

    __shared__ __align__(16) unsigned short combH[32 * 256];  // [emb|h|s] hi
    __shared__ __align__(16) unsigned short combM[32 * 256];  // mid
    __shared__ __align__(16) unsigned short combL[32 * 256];  // lo
    __shared__ __align__(16) float hbuf[32 * 128];            // f32 h (for pv)
    __shared__ __align__(16) float scratch[32 * 512];         // Y chunk / gate preacts (64KB)
    __shared__ float posb[64];
    __shared__ float pvbuf[64];
    __shared__ float red[256];
    __shared__ unsigned char binTab[1024];
    __shared__ unsigned char usedList[64];
    __shared__ unsigned char binSlotG[64];
    __shared__ int nUsedS;
    __shared__ unsigned usedMask[2];
    __shared__ float biasL[512], beL[64], bpL[64], WeL[128], WoutL[256], boutL[2];

    const int tid = threadIdx.x;
    const int lane = tid & 63;
    const int wv = tid >> 6;
    const int b = blockIdx.x;

    // preload small constants
    if (tid < 512) biasL[tid] = (tid < 128) ? bi[tid] : (tid < 256) ? bfv[tid - 128]
                              : (tid < 384) ? bo[tid - 256] : bg[tid - 384];
    if (tid < 64) { beL[tid] = be[tid]; bpL[tid] = bp[tid]; }
    if (tid < 128) WeL[tid] = We[tid];
    if (tid < 256) WoutL[tid] = Wout[tid];
    if (tid < 2) boutL[tid] = bout[tid];
    for (int x = tid; x < 32 * 256; x += 512) { combH[x] = 0; combM[x] = 0; combL[x] = 0; }
    for (int x = tid; x < 32 * 128; x += 512) hbuf[x] = 0.f;
    float creg[8];
#pragma unroll
    for (int r = 0; r < 8; ++r) creg[r] = 0.f;
    __syncthreads();

    const float gnorm = (float)(2.0 / 7.0);
    const int gi = tid >> 4;        // ped for gather/cell/emb phases
    const int gg = tid & 15;

    for (int t = 0; t < NSTEPS; ++t) {
        // ---------- E_obs: positions + embedding ----------
        if (t < OBS_T) {
            if (tid < 64) posb[tid] = obs_abs[t * 2048 + b * 64 + tid];
            {
                int e0 = gg * 4;
                float x0 = obs_rel[t * 2048 + b * 64 + gi * 2];
                float x1 = obs_rel[t * 2048 + b * 64 + gi * 2 + 1];
#pragma unroll
                for (int r = 0; r < 4; ++r) {
                    int e = e0 + r;
                    float v = x0 * WeL[e] + x1 * WeL[64 + e] + beL[e];
                    int ci = gi * 256 + (e ^ ((gi & 7) << 3));
                    store3(combH, combM, combL, ci, v);
                }
            }
        }
        if (tid < 2) usedMask[tid] = 0u;
        __syncthreads();

        // ---------- S: social pooling ----------
        float sreg[4] = {0.f, 0.f, 0.f, 0.f};
        if (t > 0) {
            // S0: bins for all pairs
#pragma unroll
            for (int pp = 0; pp < 2; ++pp) {
                int p = tid + pp * 512;
                int i = p >> 5, j = p & 31;
                float rx = (posb[j * 2]     - posb[i * 2])     / gnorm;
                float ry = (posb[j * 2 + 1] - posb[i * 2 + 1]) / gnorm;
                rx = fminf(fmaxf(rx, -4.f), 4.f);
                ry = fminf(fmaxf(ry, -4.f), 4.f);
                int gx = (int)(rx + 4.f);
                int gy = (int)(ry + 4.f);
                int valid = (gx < 8) && (gy < 8) && (i != j);
                int bin = gy * 8 + gx;
                binTab[p] = valid ? (unsigned char)bin : (unsigned char)255;
                if (valid) atomicOr(&usedMask[bin >> 5], 1u << (bin & 31));
            }
            __syncthreads();
            // S1: compact used-bin list
            if (tid == 0) {
                int cnt = 0;
                for (int bb = 0; bb < 64; ++bb) {
                    if (usedMask[bb >> 5] & (1u << (bb & 31))) {
                        usedList[cnt] = (unsigned char)bb;
                        binSlotG[bb] = (unsigned char)cnt;
                        ++cnt;
                    } else binSlotG[bb] = (unsigned char)255;
                }
                nUsedS = cnt;
            }
            __syncthreads();
            const int nUsed = nUsedS;
            const int nChunks = (nUsed + 7) >> 3;

            // A-frags: h rows (comb cols 64..191), 3-way split, held in regs
            s8v Ah[2][4], Am[2][4], Al[2][4];
#pragma unroll
            for (int m = 0; m < 2; ++m)
#pragma unroll
                for (int ks = 0; ks < 4; ++ks) {
                    int row = m * 16 + (lane & 15);
                    int k = ks * 32 + ((lane >> 4) << 3);
                    int ci = row * 256 + ((64 + k) ^ ((row & 7) << 3));
                    Ah[m][ks] = *(const s8v*)&combH[ci];
                    Am[m][ks] = *(const s8v*)&combM[ci];
                    Al[m][ks] = *(const s8v*)&combL[ci];
                }

            for (int c = 0; c < nChunks; ++c) {
                int idx = c * 8 + wv;
                if (idx < nUsed) {
                    int bin = usedList[idx];
#pragma unroll
                    for (int nt = 0; nt < 4; ++nt) {
                        f32x4 a0 = {0.f, 0.f, 0.f, 0.f};
                        f32x4 a1 = {0.f, 0.f, 0.f, 0.f};
#pragma unroll
                        for (int ks = 0; ks < 4; ++ks) {
                            int fo = ((bin * 4 + nt) * 4 + ks) * 64 + lane;
                            s8v bh = ((const s8v*)WpH)[fo];
                            s8v bm = ((const s8v*)WpM)[fo];
                            s8v bl = ((const s8v*)WpL)[fo];
                            a0 = mfma6(Ah[0][ks], Am[0][ks], Al[0][ks], bh, bm, bl, a0);
                            a1 = mfma6(Ah[1][ks], Am[1][ks], Al[1][ks], bh, bm, bl, a1);
                        }
                        int e = nt * 16 + (lane & 15);
#pragma unroll
                        for (int r = 0; r < 4; ++r) {
                            int j0 = ((lane >> 4) << 2) + r;
                            scratch[j0 * 512 + wv * 64 + (e ^ (((j0 >> 2) & 3) << 4))] = a0[r];
                            int j1 = 16 + j0;
                            scratch[j1 * 512 + wv * 64 + (e ^ (((j1 >> 2) & 3) << 4))] = a1[r];
                        }
                    }
                }
                __syncthreads();
                // gather: s_i += Y[j, bin(i,j)]
                {
                    int e0 = gg * 4;
                    for (int j = 0; j < 32; ++j) {
                        unsigned char bb = binTab[gi * 32 + j];
                        if (bb != (unsigned char)255) {
                            unsigned char sg = binSlotG[bb];
                            if ((sg >> 3) == c) {
                                int slot = sg & 7;
                                const float4 y = *(const float4*)
                                    &scratch[j * 512 + slot * 64 + (e0 ^ (((j >> 2) & 3) << 4))];
                                sreg[0] += y.x; sreg[1] += y.y; sreg[2] += y.z; sreg[3] += y.w;
                            }
                        }
                    }
                }
                __syncthreads();
            }
        }
        // finalize s = relu(pooled + bp) -> comb cols 192..255
        {
            int e0 = gg * 4;
#pragma unroll
            for (int r = 0; r < 4; ++r) {
                float v = fmaxf(sreg[r] + bpL[e0 + r], 0.f);
                int ci = gi * 256 + ((192 + e0 + r) ^ ((gi & 7) << 3));
                store3(combH, combM, combL, ci, v);
            }
        }

        // ---------- E_pred: pv, output, pos update, embedding ----------
        if (t >= OBS_T) {
            if (tid < 256) {
                int i = tid >> 3, d = (tid >> 2) & 1, pp = tid & 3;
                float acc = 0.f;
                int k0 = pp * 32;
                for (int k = k0; k < k0 + 32; ++k)
                    acc += hbuf[i * 128 + (k ^ ((i & 7) << 2))] * WoutL[k * 2 + d];
                red[tid] = acc;
            }
            __syncthreads();
            if (tid < 64) {
                int d = tid & 1;
                float pv = red[tid * 4] + red[tid * 4 + 1] + red[tid * 4 + 2] + red[tid * 4 + 3]
                         + boutL[d];
                out[(t - OBS_T) * 2048 + b * 64 + tid] = pv;   // f32 output!
                posb[tid] += pv;
                pvbuf[tid] = pv;
            }
            __syncthreads();
            {
                int e0 = gg * 4;
                float x0 = pvbuf[gi * 2], x1 = pvbuf[gi * 2 + 1];
#pragma unroll
                for (int r = 0; r < 4; ++r) {
                    int e = e0 + r;
                    float v = x0 * WeL[e] + x1 * WeL[64 + e] + beL[e];
                    int ci = gi * 256 + (e ^ ((gi & 7) << 3));
                    store3(combH, combM, combL, ci, v);
                }
            }
        }
        __syncthreads();

        // ---------- G: gate preactivations (bf16x3 MFMA) ----------
        {
            f32x4 acc[4][2];
            f32x4 zero = {0.f, 0.f, 0.f, 0.f};
#pragma unroll
            for (int q = 0; q < 4; ++q) { acc[q][0] = zero; acc[q][1] = zero; }
            for (int ks = 0; ks < 8; ++ks) {
                s8v Ah[2], Am[2], Al[2];
#pragma unroll
                for (int m = 0; m < 2; ++m) {
                    int row = m * 16 + (lane & 15);
                    int k = ks * 32 + ((lane >> 4) << 3);
                    int ci = row * 256 + (k ^ ((row & 7) << 3));
                    Ah[m] = *(const s8v*)&combH[ci];
                    Am[m] = *(const s8v*)&combM[ci];
                    Al[m] = *(const s8v*)&combL[ci];
                }
#pragma unroll
                for (int q = 0; q < 4; ++q) {
                    int nt = wv * 4 + q;
                    int fo = (nt * 8 + ks) * 64 + lane;
                    s8v bh = ((const s8v*)W4H)[fo];
                    s8v bm = ((const s8v*)W4M)[fo];
                    s8v bl = ((const s8v*)W4L)[fo];
#pragma unroll
                    for (int m = 0; m < 2; ++m)
                        acc[q][m] = mfma6(Ah[m], Am[m], Al[m], bh, bm, bl, acc[q][m]);
                }
            }
#pragma unroll
            for (int q = 0; q < 4; ++q) {
                int nt = wv * 4 + q;
                int n = nt * 16 + (lane & 15);
#pragma unroll
                for (int m = 0; m < 2; ++m)
#pragma unroll
                    for (int r = 0; r < 4; ++r) {
                        int i = m * 16 + ((lane >> 4) << 2) + r;
                        scratch[i * 512 + (n ^ (((i >> 2) & 3) << 4))] = acc[q][m][r];
                    }
            }
        }
        __syncthreads();

        // ---------- C: LSTM cell (elementwise, f32, precise exp) ----------
        {
            int k0 = gg * 8;
            float hv[8];
#pragma unroll
            for (int r = 0; r < 8; ++r) {
                int k = k0 + r;
                int sw = ((gi >> 2) & 3) << 4;
                float pi = scratch[gi * 512 + ((      k) ^ sw)] + biasL[k];
                float pf = scratch[gi * 512 + ((128 + k) ^ sw)] + biasL[128 + k];
                float po = scratch[gi * 512 + ((256 + k) ^ sw)] + biasL[256 + k];
                float pg = scratch[gi * 512 + ((384 + k) ^ sw)] + biasL[384 + k];
                float ig = 1.f / (1.f + expf(-pi));
                float fg = 1.f / (1.f + expf(-pf));
                float og = 1.f / (1.f + expf(-po));
                float gv = tanhf(pg);
                float cv = fg * creg[r] + ig * gv;
                creg[r] = cv;
                hv[r] = og * tanhf(cv);
            }
#pragma unroll
            for (int r = 0; r < 8; ++r) {
                int k = k0 + r;
                hbuf[gi * 128 + (k ^ ((gi & 7) << 2))] = hv[r];
                int ci = gi * 256 + ((64 + k) ^ ((gi & 7) << 3));
                store3(combH, combM, combL, ci, hv[r]);
            }
        }
        __syncthreads();
    }
}

extern "C" void kernel_launch(void* const* d_in, const int* in_sizes, int n_in,
                              void* d_out, int out_size, void* d_ws, size_t ws_size,
                              hipStream_t stream) {
    const float* obs_rel = (const float*)d_in[0];
    const float* obs_abs = (const float*)d_in[1];
    // d_in[2]: seq_start_end — fixed contiguous blocks of 32, unused
    const float* We   = (const float*)d_in[3];
    const float* be   = (const float*)d_in[4];
    const float* Wp   = (const float*)d_in[5];
    const float* bp   = (const float*)d_in[6];
    const float* Wi   = (const float*)d_in[7];
    const float* bi   = (const float*)d_in[8];
    const float* Wf   = (const float*)d_in[9];
    const float* bf   = (const float*)d_in[10];
    const float* Wo   = (const float*)d_in[11];
    const float* bo   = (const float*)d_in[12];
    const float* Wg   = (const float*)d_in[13];
    const float* bg   = (const float*)d_in[14];
    const float* Wout = (const float*)d_in[15];
    const float* bout = (const float*)d_in[16];

    unsigned short* ws = (unsigned short*)d_ws;
    unsigned short* W4H = ws;
    unsigned short* W4M = W4H + 131072;
    unsigned short* W4L = W4M + 131072;
    unsigned short* WpH = W4L + 131072;
    unsigned short* WpM = WpH + 524288;
    unsigned short* WpL = WpM + 524288;

    slstm_prep<<<2560, 256, 0, stream>>>(Wp, Wi, Wf, Wo, Wg,
                                         W4H, W4M, W4L, WpH, WpM, WpL);
    slstm_main<<<32, 512, 0, stream>>>(obs_rel, obs_abs, We, be, bp, bi, bf, bo, bg,
                                       Wout, bout, W4H, W4M, W4L, WpH, WpM, WpL,
                                       (float*)d_out);
}

// Round 5
// 2111.223 us; speedup vs baseline: 1.2697x; 1.2697x over previous
//
#include <hip/hip_runtime.h>

typedef short s8v __attribute__((ext_vector_type(8)));
typedef float f32x4 __attribute__((ext_vector_type(4)));

#define OBS_T 8
#define NSTEPS 20

__device__ __forceinline__ unsigned short f2bf(float x) {
    unsigned u = __float_as_uint(x);
    u = (u + 0x7FFFu + ((u >> 16) & 1u)) >> 16;
    return (unsigned short)u;
}
__device__ __forceinline__ float bf2f(unsigned short h) {
    return __uint_as_float(((unsigned)h) << 16);
}

// 6-product bf16x3 accumulate (gates): ordered small->large.
__device__ __forceinline__ f32x4 mfma6(s8v ah, s8v am, s8v al,
                                       s8v bh, s8v bm, s8v bl, f32x4 acc) {
    acc = __builtin_amdgcn_mfma_f32_16x16x32_bf16(al, bh, acc, 0, 0, 0);
    acc = __builtin_amdgcn_mfma_f32_16x16x32_bf16(ah, bl, acc, 0, 0, 0);
    acc = __builtin_amdgcn_mfma_f32_16x16x32_bf16(am, bm, acc, 0, 0, 0);
    acc = __builtin_amdgcn_mfma_f32_16x16x32_bf16(am, bh, acc, 0, 0, 0);
    acc = __builtin_amdgcn_mfma_f32_16x16x32_bf16(ah, bm, acc, 0, 0, 0);
    acc = __builtin_amdgcn_mfma_f32_16x16x32_bf16(ah, bh, acc, 0, 0, 0);
    return acc;
}

__device__ __forceinline__ void store3(unsigned short* H, unsigned short* M,
                                       unsigned short* L, int ci, float v) {
    unsigned short h = f2bf(v);
    float r1 = v - bf2f(h);
    unsigned short m = f2bf(r1);
    H[ci] = h; M[ci] = m; L[ci] = f2bf(r1 - bf2f(m));
}

// ---------------- prep: pack weight fragments ----------------
// W4frag (bf16x3): [nt(32)][ks(8)][lane(64)][j(8)]  n=nt*16+(l&15), k=ks*32+(l>>4)*8+j
// Wpfrag (bf16x2): [bin(64)][nt(4)][ks(4)][lane(64)][j(8)] e=nt*16+(l&15), k=ks*32+(l>>4)*8+j
__global__ void slstm_prep(const float* __restrict__ Wp,
                           const float* __restrict__ Wi, const float* __restrict__ Wf,
                           const float* __restrict__ Wo, const float* __restrict__ Wg,
                           unsigned short* __restrict__ W4H, unsigned short* __restrict__ W4M,
                           unsigned short* __restrict__ W4L,
                           unsigned short* __restrict__ WpH, unsigned short* __restrict__ WpL) {
    int x = blockIdx.x * blockDim.x + threadIdx.x;
    const int NW4 = 32 * 8 * 64 * 8;      // 131072
    const int NWP = 64 * 4 * 4 * 64 * 8;  // 524288
    if (x < NW4) {
        int j = x & 7, lane = (x >> 3) & 63, ks = (x >> 9) & 7, nt = x >> 12;
        int n = nt * 16 + (lane & 15);
        int k = ks * 32 + ((lane >> 4) << 3) + j;
        int gt = n >> 7, col = n & 127;
        const float* W = (gt == 0) ? Wi : (gt == 1) ? Wf : (gt == 2) ? Wo : Wg;
        float v = W[k * 128 + col];
        unsigned short h = f2bf(v);
        float r1 = v - bf2f(h);
        unsigned short m = f2bf(r1);
        W4H[x] = h; W4M[x] = m; W4L[x] = f2bf(r1 - bf2f(m));
    } else if (x < NW4 + NWP) {
        int y = x - NW4;
        int j = y & 7, lane = (y >> 3) & 63, ks = (y >> 9) & 3, nt = (y >> 11) & 3, bin = y >> 13;
        int e = nt * 16 + (lane & 15);
        int k = ks * 32 + ((lane >> 4) << 3) + j;
        float v = Wp[(bin * 128 + k) * 64 + e];
        unsigned short h = f2bf(v);
        WpH[y] = h; WpL[y] = f2bf(v - bf2f(h));
    }
}

// ---------------- main persistent kernel: 1 WG per sequence ----------------
__global__ __launch_bounds__(512, 2) void slstm_main(
    const float* __restrict__ obs_rel, const float* __restrict__ obs_abs,
    const float* __restrict__ We, const float* __restrict__ be,
    const float* __restrict__ bp,
    const float* __restrict__ bi, const float* __restrict__ bfv,
    const float* __restrict__ bo, const float* __restrict__ bg,
    const float* __restrict__ Wout, const float* __restrict__ bout,
    const unsigned short* __restrict__ W4H, const unsigned short* __restrict__ W4M,
    const unsigned short* __restrict__ W4L,
    const unsigned short* __restrict__ WpH, const unsigned short* __restrict__ WpL,
    float* __restrict__ out) {

    __shared__ __align__(16) unsigned short combH[32 * 256];  // [emb|h|s] hi
    __shared__ __align__(16) unsigned short combM[32 * 256];  // mid
    __shared__ __align__(16) unsigned short combL[32 * 256];  // lo
    __shared__ __align__(16) float hbuf[32 * 128];            // f32 h (for pv)
    __shared__ __align__(16) float scratch[32 * 512];         // Y chunk / gate preacts (64KB)
    __shared__ float posb[64];
    __shared__ float pvbuf[64];
    __shared__ float red[256];
    __shared__ unsigned char binTab[1024];
    __shared__ unsigned char usedList[64];
    __shared__ unsigned char binSlotG[64];
    __shared__ int nUsedS;
    __shared__ unsigned usedMask[2];
    __shared__ unsigned jm[4];   // [0..1]: bins with some j<16; [2..3]: some j>=16
    __shared__ float biasL[512], beL[64], bpL[64], WeL[128], WoutL[256], boutL[2];

    const int tid = threadIdx.x;
    const int lane = tid & 63;
    const int wv = tid >> 6;
    const int b = blockIdx.x;

    if (tid < 512) biasL[tid] = (tid < 128) ? bi[tid] : (tid < 256) ? bfv[tid - 128]
                              : (tid < 384) ? bo[tid - 256] : bg[tid - 384];
    if (tid < 64) { beL[tid] = be[tid]; bpL[tid] = bp[tid]; }
    if (tid < 128) WeL[tid] = We[tid];
    if (tid < 256) WoutL[tid] = Wout[tid];
    if (tid < 2) boutL[tid] = bout[tid];
    for (int x = tid; x < 32 * 256; x += 512) { combH[x] = 0; combM[x] = 0; combL[x] = 0; }
    for (int x = tid; x < 32 * 128; x += 512) hbuf[x] = 0.f;
    float creg[8];
#pragma unroll
    for (int r = 0; r < 8; ++r) creg[r] = 0.f;
    __syncthreads();

    const float gnorm = (float)(2.0 / 7.0);
    const int gi = tid >> 4;
    const int gg = tid & 15;

    for (int t = 0; t < NSTEPS; ++t) {
        // ---------- E_obs: positions + embedding ----------
        if (t < OBS_T) {
            if (tid < 64) posb[tid] = obs_abs[t * 2048 + b * 64 + tid];
            {
                int e0 = gg * 4;
                float x0 = obs_rel[t * 2048 + b * 64 + gi * 2];
                float x1 = obs_rel[t * 2048 + b * 64 + gi * 2 + 1];
#pragma unroll
                for (int r = 0; r < 4; ++r) {
                    int e = e0 + r;
                    float v = x0 * WeL[e] + x1 * WeL[64 + e] + beL[e];
                    int ci = gi * 256 + (e ^ ((gi & 7) << 3));
                    store3(combH, combM, combL, ci, v);
                }
            }
        }
        if (tid < 2) usedMask[tid] = 0u;
        if (tid < 4) jm[tid] = 0u;
        __syncthreads();

        // ---------- S: social pooling ----------
        float sreg[4] = {0.f, 0.f, 0.f, 0.f};
        if (t > 0) {
            // S0: bins for all pairs
#pragma unroll
            for (int pp = 0; pp < 2; ++pp) {
                int p = tid + pp * 512;
                int i = p >> 5, j = p & 31;
                float rx = (posb[j * 2]     - posb[i * 2])     / gnorm;
                float ry = (posb[j * 2 + 1] - posb[i * 2 + 1]) / gnorm;
                rx = fminf(fmaxf(rx, -4.f), 4.f);
                ry = fminf(fmaxf(ry, -4.f), 4.f);
                int gx = (int)(rx + 4.f);
                int gy = (int)(ry + 4.f);
                int valid = (gx < 8) && (gy < 8) && (i != j);
                int bin = gy * 8 + gx;
                binTab[p] = valid ? (unsigned char)bin : (unsigned char)255;
                if (valid) {
                    atomicOr(&usedMask[bin >> 5], 1u << (bin & 31));
                    atomicOr(&jm[((j < 16) ? 0 : 2) + (bin >> 5)], 1u << (bin & 31));
                }
            }
            __syncthreads();
            // S1: compact used-bin list
            if (tid == 0) {
                int cnt = 0;
                for (int bb = 0; bb < 64; ++bb) {
                    if (usedMask[bb >> 5] & (1u << (bb & 31))) {
                        usedList[cnt] = (unsigned char)bb;
                        binSlotG[bb] = (unsigned char)cnt;
                        ++cnt;
                    } else binSlotG[bb] = (unsigned char)255;
                }
                nUsedS = cnt;
            }
            __syncthreads();
            const int nUsed = nUsedS;
            const int nChunks = (nUsed + 7) >> 3;

            // A-frags: h rows (comb cols 64..191), H+M splits held in regs
            s8v Ah[2][4], Am[2][4];
#pragma unroll
            for (int m = 0; m < 2; ++m)
#pragma unroll
                for (int ks = 0; ks < 4; ++ks) {
                    int row = m * 16 + (lane & 15);
                    int k = ks * 32 + ((lane >> 4) << 3);
                    int ci = row * 256 + ((64 + k) ^ ((row & 7) << 3));
                    Ah[m][ks] = *(const s8v*)&combH[ci];
                    Am[m][ks] = *(const s8v*)&combM[ci];
                }

            for (int c = 0; c < nChunks; ++c) {
                int idx = c * 8 + wv;
                if (idx < nUsed) {
                    int bin = usedList[idx];
                    const bool do0 = (jm[bin >> 5]     >> (bin & 31)) & 1;  // any j<16
                    const bool do1 = (jm[2 + (bin >> 5)] >> (bin & 31)) & 1;  // any j>=16
#pragma unroll
                    for (int nt = 0; nt < 4; ++nt) {
                        // batch the 8 B-frag loads for this nt (MLP)
                        s8v bh[4], bl[4];
#pragma unroll
                        for (int ks = 0; ks < 4; ++ks) {
                            int fo = ((bin * 4 + nt) * 4 + ks) * 64 + lane;
                            bh[ks] = ((const s8v*)WpH)[fo];
                            bl[ks] = ((const s8v*)WpL)[fo];
                        }
                        f32x4 a0 = {0.f, 0.f, 0.f, 0.f};
                        f32x4 a1 = {0.f, 0.f, 0.f, 0.f};
                        if (do0) {
#pragma unroll
                            for (int ks = 0; ks < 4; ++ks) {
                                a0 = __builtin_amdgcn_mfma_f32_16x16x32_bf16(Am[0][ks], bh[ks], a0, 0, 0, 0);
                                a0 = __builtin_amdgcn_mfma_f32_16x16x32_bf16(Ah[0][ks], bl[ks], a0, 0, 0, 0);
                                a0 = __builtin_amdgcn_mfma_f32_16x16x32_bf16(Ah[0][ks], bh[ks], a0, 0, 0, 0);
                            }
                        }
                        if (do1) {
#pragma unroll
                            for (int ks = 0; ks < 4; ++ks) {
                                a1 = __builtin_amdgcn_mfma_f32_16x16x32_bf16(Am[1][ks], bh[ks], a1, 0, 0, 0);
                                a1 = __builtin_amdgcn_mfma_f32_16x16x32_bf16(Ah[1][ks], bl[ks], a1, 0, 0, 0);
                                a1 = __builtin_amdgcn_mfma_f32_16x16x32_bf16(Ah[1][ks], bh[ks], a1, 0, 0, 0);
                            }
                        }
                        int e = nt * 16 + (lane & 15);
                        if (do0) {
#pragma unroll
                            for (int r = 0; r < 4; ++r) {
                                int j0 = ((lane >> 4) << 2) + r;
                                scratch[j0 * 512 + wv * 64 + (e ^ (((j0 >> 2) & 3) << 4))] = a0[r];
                            }
                        }
                        if (do1) {
#pragma unroll
                            for (int r = 0; r < 4; ++r) {
                                int j1 = 16 + ((lane >> 4) << 2) + r;
                                scratch[j1 * 512 + wv * 64 + (e ^ (((j1 >> 2) & 3) << 4))] = a1[r];
                            }
                        }
                    }
                }
                __syncthreads();
                // gather: s_i += Y[j, bin(i,j)]
                {
                    int e0 = gg * 4;
                    for (int j = 0; j < 32; ++j) {
                        unsigned char bb = binTab[gi * 32 + j];
                        if (bb != (unsigned char)255) {
                            unsigned char sg = binSlotG[bb];
                            if ((sg >> 3) == c) {
                                int slot = sg & 7;
                                const float4 y = *(const float4*)
                                    &scratch[j * 512 + slot * 64 + (e0 ^ (((j >> 2) & 3) << 4))];
                                sreg[0] += y.x; sreg[1] += y.y; sreg[2] += y.z; sreg[3] += y.w;
                            }
                        }
                    }
                }
                __syncthreads();
            }
        }
        // finalize s = relu(pooled + bp) -> comb cols 192..255
        {
            int e0 = gg * 4;
#pragma unroll
            for (int r = 0; r < 4; ++r) {
                float v = fmaxf(sreg[r] + bpL[e0 + r], 0.f);
                int ci = gi * 256 + ((192 + e0 + r) ^ ((gi & 7) << 3));
                store3(combH, combM, combL, ci, v);
            }
        }

        // ---------- E_pred: pv, output, pos update, embedding ----------
        if (t >= OBS_T) {
            if (tid < 256) {
                int i = tid >> 3, d = (tid >> 2) & 1, pp = tid & 3;
                float acc = 0.f;
                int k0 = pp * 32;
                for (int k = k0; k < k0 + 32; ++k)
                    acc += hbuf[i * 128 + (k ^ ((i & 7) << 2))] * WoutL[k * 2 + d];
                red[tid] = acc;
            }
            __syncthreads();
            if (tid < 64) {
                int d = tid & 1;
                float pv = red[tid * 4] + red[tid * 4 + 1] + red[tid * 4 + 2] + red[tid * 4 + 3]
                         + boutL[d];
                out[(t - OBS_T) * 2048 + b * 64 + tid] = pv;
                posb[tid] += pv;
                pvbuf[tid] = pv;
            }
            __syncthreads();
            {
                int e0 = gg * 4;
                float x0 = pvbuf[gi * 2], x1 = pvbuf[gi * 2 + 1];
#pragma unroll
                for (int r = 0; r < 4; ++r) {
                    int e = e0 + r;
                    float v = x0 * WeL[e] + x1 * WeL[64 + e] + beL[e];
                    int ci = gi * 256 + (e ^ ((gi & 7) << 3));
                    store3(combH, combM, combL, ci, v);
                }
            }
        }
        __syncthreads();

        // ---------- G: gate preactivations (bf16x3 MFMA, batched loads) ----------
        {
            f32x4 acc[4][2];
            f32x4 zero = {0.f, 0.f, 0.f, 0.f};
#pragma unroll
            for (int q = 0; q < 4; ++q) { acc[q][0] = zero; acc[q][1] = zero; }
            for (int ks = 0; ks < 8; ++ks) {
                s8v Ah[2], Am[2], Al[2];
#pragma unroll
                for (int m = 0; m < 2; ++m) {
                    int row = m * 16 + (lane & 15);
                    int k = ks * 32 + ((lane >> 4) << 3);
                    int ci = row * 256 + (k ^ ((row & 7) << 3));
                    Ah[m] = *(const s8v*)&combH[ci];
                    Am[m] = *(const s8v*)&combM[ci];
                    Al[m] = *(const s8v*)&combL[ci];
                }
                // batch all 12 B-frag loads for this ks (MLP)
                s8v bh[4], bm[4], bl[4];
#pragma unroll
                for (int q = 0; q < 4; ++q) {
                    int nt = wv * 4 + q;
                    int fo = (nt * 8 + ks) * 64 + lane;
                    bh[q] = ((const s8v*)W4H)[fo];
                    bm[q] = ((const s8v*)W4M)[fo];
                    bl[q] = ((const s8v*)W4L)[fo];
                }
#pragma unroll
                for (int q = 0; q < 4; ++q)
#pragma unroll
                    for (int m = 0; m < 2; ++m)
                        acc[q][m] = mfma6(Ah[m], Am[m], Al[m], bh[q], bm[q], bl[q], acc[q][m]);
            }
#pragma unroll
            for (int q = 0; q < 4; ++q) {
                int nt = wv * 4 + q;
                int n = nt * 16 + (lane & 15);
#pragma unroll
                for (int m = 0; m < 2; ++m)
#pragma unroll
                    for (int r = 0; r < 4; ++r) {
                        int i = m * 16 + ((lane >> 4) << 2) + r;
                        scratch[i * 512 + (n ^ (((i >> 2) & 3) << 4))] = acc[q][m][r];
                    }
            }
        }
        __syncthreads();

        // ---------- C: LSTM cell (elementwise, f32) ----------
        {
            int k0 = gg * 8;
            float hv[8];
#pragma unroll
            for (int r = 0; r < 8; ++r) {
                int k = k0 + r;
                int sw = ((gi >> 2) & 3) << 4;
                float pi = scratch[gi * 512 + ((      k) ^ sw)] + biasL[k];
                float pf = scratch[gi * 512 + ((128 + k) ^ sw)] + biasL[128 + k];
                float po = scratch[gi * 512 + ((256 + k) ^ sw)] + biasL[256 + k];
                float pg = scratch[gi * 512 + ((384 + k) ^ sw)] + biasL[384 + k];
                float ig = 1.f / (1.f + expf(-pi));
                float fg = 1.f / (1.f + expf(-pf));
                float og = 1.f / (1.f + expf(-po));
                float gv = tanhf(pg);
                float cv = fg * creg[r] + ig * gv;
                creg[r] = cv;
                hv[r] = og * tanhf(cv);
            }
#pragma unroll
            for (int r = 0; r < 8; ++r) {
                int k = k0 + r;
                hbuf[gi * 128 + (k ^ ((gi & 7) << 2))] = hv[r];
                int ci = gi * 256 + ((64 + k) ^ ((gi & 7) << 3));
                store3(combH, combM, combL, ci, hv[r]);
            }
        }
        __syncthreads();
    }
}

extern "C" void kernel_launch(void* const* d_in, const int* in_sizes, int n_in,
                              void* d_out, int out_size, void* d_ws, size_t ws_size,
                              hipStream_t stream) {
    const float* obs_rel = (const float*)d_in[0];
    const float* obs_abs = (const float*)d_in[1];
    // d_in[2]: seq_start_end — fixed contiguous blocks of 32, unused
    const float* We   = (const float*)d_in[3];
    const float* be   = (const float*)d_in[4];
    const float* Wp   = (const float*)d_in[5];
    const float* bp   = (const float*)d_in[6];
    const float* Wi   = (const float*)d_in[7];
    const float* bi   = (const float*)d_in[8];
    const float* Wf   = (const float*)d_in[9];
    const float* bf   = (const float*)d_in[10];
    const float* Wo   = (const float*)d_in[11];
    const float* bo   = (const float*)d_in[12];
    const float* Wg   = (const float*)d_in[13];
    const float* bg   = (const float*)d_in[14];
    const float* Wout = (const float*)d_in[15];
    const float* bout = (const float*)d_in[16];

    unsigned short* ws = (unsigned short*)d_ws;
    unsigned short* W4H = ws;
    unsigned short* W4M = W4H + 131072;
    unsigned short* W4L = W4M + 131072;
    unsigned short* WpH = W4L + 131072;
    unsigned short* WpL = WpH + 524288;

    slstm_prep<<<2560, 256, 0, stream>>>(Wp, Wi, Wf, Wo, Wg,
                                         W4H, W4M, W4L, WpH, WpL);
    slstm_main<<<32, 512, 0, stream>>>(obs_rel, obs_abs, We, be, bp, bi, bf, bo, bg,
                                       Wout, bout, W4H, W4M, W4L, WpH, WpL,
                                       (float*)d_out);
}

// Round 6
// 1417.550 us; speedup vs baseline: 1.8910x; 1.4893x over previous
//
#include <hip/hip_runtime.h>

typedef short s8v __attribute__((ext_vector_type(8)));
typedef float f32x4 __attribute__((ext_vector_type(4)));

#define OBS_T 8
#define NSTEPS 20

__device__ __forceinline__ unsigned short f2bf(float x) {
    unsigned u = __float_as_uint(x);
    u = (u + 0x7FFFu + ((u >> 16) & 1u)) >> 16;
    return (unsigned short)u;
}
__device__ __forceinline__ float bf2f(unsigned short h) {
    return __uint_as_float(((unsigned)h) << 16);
}

// x2 split store: H + M (M = bf16(v - H)); residual ~2^-16 rel, proven sufficient
// (rounds 1 vs 2: x2 and x3 gave bit-identical bf16-rounded trajectories).
__device__ __forceinline__ void store2(unsigned short* H, unsigned short* M,
                                       int ci, float v) {
    unsigned short h = f2bf(v);
    H[ci] = h; M[ci] = f2bf(v - bf2f(h));
}

// ---------------- prep: pack x2-split bf16 weight fragments ----------------
// W4frag (x2): [nt(32)][ks(8)][lane(64)][j(8)]  n=nt*16+(l&15), k=ks*32+(l>>4)*8+j
// Wpfrag (x2): [bin(64)][nt(4)][ks(4)][lane(64)][j(8)] e=nt*16+(l&15), k=ks*32+(l>>4)*8+j
__global__ void slstm_prep(const float* __restrict__ Wp,
                           const float* __restrict__ Wi, const float* __restrict__ Wf,
                           const float* __restrict__ Wo, const float* __restrict__ Wg,
                           unsigned short* __restrict__ W4H, unsigned short* __restrict__ W4L,
                           unsigned short* __restrict__ WpH, unsigned short* __restrict__ WpL) {
    int x = blockIdx.x * blockDim.x + threadIdx.x;
    const int NW4 = 32 * 8 * 64 * 8;      // 131072
    const int NWP = 64 * 4 * 4 * 64 * 8;  // 524288
    if (x < NW4) {
        int j = x & 7, lane = (x >> 3) & 63, ks = (x >> 9) & 7, nt = x >> 12;
        int n = nt * 16 + (lane & 15);
        int k = ks * 32 + ((lane >> 4) << 3) + j;
        int gt = n >> 7, col = n & 127;
        const float* W = (gt == 0) ? Wi : (gt == 1) ? Wf : (gt == 2) ? Wo : Wg;
        float v = W[k * 128 + col];
        unsigned short h = f2bf(v);
        W4H[x] = h; W4L[x] = f2bf(v - bf2f(h));
    } else if (x < NW4 + NWP) {
        int y = x - NW4;
        int j = y & 7, lane = (y >> 3) & 63, ks = (y >> 9) & 3, nt = (y >> 11) & 3, bin = y >> 13;
        int e = nt * 16 + (lane & 15);
        int k = ks * 32 + ((lane >> 4) << 3) + j;
        float v = Wp[(bin * 128 + k) * 64 + e];
        unsigned short h = f2bf(v);
        WpH[y] = h; WpL[y] = f2bf(v - bf2f(h));
    }
}

// ---------------- main persistent kernel: 1 WG per sequence ----------------
__global__ __launch_bounds__(512, 2) void slstm_main(
    const float* __restrict__ obs_rel, const float* __restrict__ obs_abs,
    const float* __restrict__ We, const float* __restrict__ be,
    const float* __restrict__ bp,
    const float* __restrict__ bi, const float* __restrict__ bfv,
    const float* __restrict__ bo, const float* __restrict__ bg,
    const float* __restrict__ Wout, const float* __restrict__ bout,
    const unsigned short* __restrict__ W4H, const unsigned short* __restrict__ W4L,
    const unsigned short* __restrict__ WpH, const unsigned short* __restrict__ WpL,
    float* __restrict__ out) {

    __shared__ __align__(16) unsigned short combH[32 * 256];  // [emb|h|s] hi
    __shared__ __align__(16) unsigned short combM[32 * 256];  // lo (x2 split)
    __shared__ __align__(16) float hbuf[32 * 128];            // f32 h (for pv)
    __shared__ __align__(16) float scratch[32 * 512];         // Y chunk / gate preacts (64KB)
    __shared__ float posb[64];
    __shared__ float pvbuf[64];
    __shared__ float red[256];
    __shared__ unsigned char binTab[1024];
    __shared__ unsigned char usedList[64];
    __shared__ unsigned char binSlotG[64];
    __shared__ unsigned short glist[1024];                    // per-i pair list, chunk-sorted
    __shared__ unsigned long long gstartPacked[32];           // 9 x 5-bit prefix per i
    __shared__ int nUsedS;
    __shared__ unsigned usedMask[2];
    __shared__ unsigned jm[4];   // [0..1]: bins with some j<16; [2..3]: some j>=16
    __shared__ float biasL[512], beL[64], bpL[64], WeL[128], WoutL[256], boutL[2];

    const int tid = threadIdx.x;
    const int lane = tid & 63;
    const int wv = tid >> 6;
    const int b = blockIdx.x;

    if (tid < 512) biasL[tid] = (tid < 128) ? bi[tid] : (tid < 256) ? bfv[tid - 128]
                              : (tid < 384) ? bo[tid - 256] : bg[tid - 384];
    if (tid < 64) { beL[tid] = be[tid]; bpL[tid] = bp[tid]; }
    if (tid < 128) WeL[tid] = We[tid];
    if (tid < 256) WoutL[tid] = Wout[tid];
    if (tid < 2) boutL[tid] = bout[tid];
    for (int x = tid; x < 32 * 256; x += 512) { combH[x] = 0; combM[x] = 0; }
    for (int x = tid; x < 32 * 128; x += 512) hbuf[x] = 0.f;
    float creg[8];
#pragma unroll
    for (int r = 0; r < 8; ++r) creg[r] = 0.f;
    __syncthreads();

    const float gnorm = (float)(2.0 / 7.0);
    const int gi = tid >> 4;
    const int gg = tid & 15;

    for (int t = 0; t < NSTEPS; ++t) {
        // ---------- E_obs: positions + embedding ----------
        if (t < OBS_T) {
            if (tid < 64) posb[tid] = obs_abs[t * 2048 + b * 64 + tid];
            {
                int e0 = gg * 4;
                float x0 = obs_rel[t * 2048 + b * 64 + gi * 2];
                float x1 = obs_rel[t * 2048 + b * 64 + gi * 2 + 1];
#pragma unroll
                for (int r = 0; r < 4; ++r) {
                    int e = e0 + r;
                    float v = x0 * WeL[e] + x1 * WeL[64 + e] + beL[e];
                    store2(combH, combM, gi * 256 + (e ^ ((gi & 7) << 3)), v);
                }
            }
        }
        if (tid < 2) usedMask[tid] = 0u;
        if (tid < 4) jm[tid] = 0u;
        __syncthreads();

        // ---------- S: social pooling ----------
        float sreg[4] = {0.f, 0.f, 0.f, 0.f};
        if (t > 0) {
            // S0: bins for all pairs
#pragma unroll
            for (int pp = 0; pp < 2; ++pp) {
                int p = tid + pp * 512;
                int i = p >> 5, j = p & 31;
                float rx = (posb[j * 2]     - posb[i * 2])     / gnorm;
                float ry = (posb[j * 2 + 1] - posb[i * 2 + 1]) / gnorm;
                rx = fminf(fmaxf(rx, -4.f), 4.f);
                ry = fminf(fmaxf(ry, -4.f), 4.f);
                int gx = (int)(rx + 4.f);
                int gy = (int)(ry + 4.f);
                int valid = (gx < 8) && (gy < 8) && (i != j);
                int bin = gy * 8 + gx;
                binTab[p] = valid ? (unsigned char)bin : (unsigned char)255;
                if (valid) {
                    atomicOr(&usedMask[bin >> 5], 1u << (bin & 31));
                    atomicOr(&jm[((j < 16) ? 0 : 2) + (bin >> 5)], 1u << (bin & 31));
                }
            }
            __syncthreads();
            // S1: compact used-bin list
            if (tid == 0) {
                int cnt = 0;
                for (int bb = 0; bb < 64; ++bb) {
                    if (usedMask[bb >> 5] & (1u << (bb & 31))) {
                        usedList[cnt] = (unsigned char)bb;
                        binSlotG[bb] = (unsigned char)cnt;
                        ++cnt;
                    } else binSlotG[bb] = (unsigned char)255;
                }
                nUsedS = cnt;
            }
            __syncthreads();
            const int nUsed = nUsedS;
            const int nChunks = (nUsed + 7) >> 3;

            // A-frags: h rows (comb cols 64..191), x2 split, held in regs
            s8v Ah[2][4], Am[2][4];
#pragma unroll
            for (int m = 0; m < 2; ++m)
#pragma unroll
                for (int ks = 0; ks < 4; ++ks) {
                    int row = m * 16 + (lane & 15);
                    int k = ks * 32 + ((lane >> 4) << 3);
                    int ci = row * 256 + ((64 + k) ^ ((row & 7) << 3));
                    Ah[m][ks] = *(const s8v*)&combH[ci];
                    Am[m][ks] = *(const s8v*)&combM[ci];
                }

            // build per-(i,chunk) gather lists (tid<32), done before chunk-0 barrier.
            if (tid < 32) {
                const int i = tid;
                unsigned rw[8];
#pragma unroll
                for (int w = 0; w < 8; ++w)
                    rw[w] = *(const unsigned*)&binTab[i * 32 + w * 4];
                unsigned long long cntp = 0;
#pragma unroll
                for (int j = 0; j < 32; ++j) {
                    unsigned bb = (rw[j >> 2] >> ((j & 3) * 8)) & 255u;
                    if (bb != 255u) {
                        int c = binSlotG[bb] >> 3;
                        cntp += 1ull << (5 * c);
                    }
                }
                unsigned long long pre = 0; unsigned sum = 0;
#pragma unroll
                for (int c = 0; c < 8; ++c) {
                    pre |= (unsigned long long)sum << (5 * c);
                    sum += (unsigned)((cntp >> (5 * c)) & 31);
                }
                gstartPacked[i] = pre | ((unsigned long long)sum << 40);
                unsigned long long pos = pre;
#pragma unroll
                for (int j = 0; j < 32; ++j) {
                    unsigned bb = (rw[j >> 2] >> ((j & 3) * 8)) & 255u;
                    if (bb != 255u) {
                        int sg = binSlotG[bb];
                        int c = sg >> 3;
                        int p = (int)((pos >> (5 * c)) & 31);
                        glist[i * 32 + p] = (unsigned short)((sg << 5) | j);
                        pos += 1ull << (5 * c);
                    }
                }
            }

            for (int c = 0; c < nChunks; ++c) {
                int idx = c * 8 + wv;
                if (idx < nUsed) {
                    int bin = usedList[idx];
                    const bool do0 = (jm[bin >> 5]       >> (bin & 31)) & 1;
                    const bool do1 = (jm[2 + (bin >> 5)] >> (bin & 31)) & 1;
                    s8v bh[2][4], bl[2][4];
#pragma unroll
                    for (int ks = 0; ks < 4; ++ks) {
                        int fo = ((bin * 4 + 0) * 4 + ks) * 64 + lane;
                        bh[0][ks] = ((const s8v*)WpH)[fo];
                        bl[0][ks] = ((const s8v*)WpL)[fo];
                    }
#pragma unroll
                    for (int nt = 0; nt < 4; ++nt) {
                        const int cb = nt & 1;
                        if (nt < 3) {   // prefetch next nt's frags into other buffer
#pragma unroll
                            for (int ks = 0; ks < 4; ++ks) {
                                int fo = ((bin * 4 + nt + 1) * 4 + ks) * 64 + lane;
                                bh[cb ^ 1][ks] = ((const s8v*)WpH)[fo];
                                bl[cb ^ 1][ks] = ((const s8v*)WpL)[fo];
                            }
                        }
                        f32x4 a0 = {0.f, 0.f, 0.f, 0.f};
                        f32x4 a1 = {0.f, 0.f, 0.f, 0.f};
                        if (do0) {
#pragma unroll
                            for (int ks = 0; ks < 4; ++ks) {
                                a0 = __builtin_amdgcn_mfma_f32_16x16x32_bf16(Am[0][ks], bh[cb][ks], a0, 0, 0, 0);
                                a0 = __builtin_amdgcn_mfma_f32_16x16x32_bf16(Ah[0][ks], bl[cb][ks], a0, 0, 0, 0);
                                a0 = __builtin_amdgcn_mfma_f32_16x16x32_bf16(Ah[0][ks], bh[cb][ks], a0, 0, 0, 0);
                            }
                        }
                        if (do1) {
#pragma unroll
                            for (int ks = 0; ks < 4; ++ks) {
                                a1 = __builtin_amdgcn_mfma_f32_16x16x32_bf16(Am[1][ks], bh[cb][ks], a1, 0, 0, 0);
                                a1 = __builtin_amdgcn_mfma_f32_16x16x32_bf16(Ah[1][ks], bl[cb][ks], a1, 0, 0, 0);
                                a1 = __builtin_amdgcn_mfma_f32_16x16x32_bf16(Ah[1][ks], bh[cb][ks], a1, 0, 0, 0);
                            }
                        }
                        int e = nt * 16 + (lane & 15);
                        if (do0) {
#pragma unroll
                            for (int r = 0; r < 4; ++r) {
                                int j0 = ((lane >> 4) << 2) + r;
                                scratch[j0 * 512 + wv * 64 + (e ^ (((j0 >> 2) & 3) << 4))] = a0[r];
                            }
                        }
                        if (do1) {
#pragma unroll
                            for (int r = 0; r < 4; ++r) {
                                int j1 = 16 + ((lane >> 4) << 2) + r;
                                scratch[j1 * 512 + wv * 64 + (e ^ (((j1 >> 2) & 3) << 4))] = a1[r];
                            }
                        }
                    }
                }
                __syncthreads();
                // gather via per-(i,chunk) lists
                {
                    const int e0 = gg * 4;
                    unsigned long long sp = gstartPacked[gi];
                    int p0 = (int)((sp >> (5 * c)) & 31);
                    int p1 = (int)((sp >> (5 * c + 5)) & 31);
                    for (int p = p0; p < p1; ++p) {
                        unsigned en = glist[gi * 32 + p];
                        int slot = (en >> 5) & 7;
                        int j = en & 31;
                        const float4 y = *(const float4*)
                            &scratch[j * 512 + slot * 64 + (e0 ^ (((j >> 2) & 3) << 4))];
                        sreg[0] += y.x; sreg[1] += y.y; sreg[2] += y.z; sreg[3] += y.w;
                    }
                }
                __syncthreads();
            }
        }
        // finalize s = relu(pooled + bp) -> comb cols 192..255
        {
            int e0 = gg * 4;
#pragma unroll
            for (int r = 0; r < 4; ++r) {
                float v = fmaxf(sreg[r] + bpL[e0 + r], 0.f);
                store2(combH, combM, gi * 256 + ((192 + e0 + r) ^ ((gi & 7) << 3)), v);
            }
        }

        // ---------- E_pred: pv, output, pos update, embedding ----------
        if (t >= OBS_T) {
            if (tid < 256) {
                int i = tid >> 3, d = (tid >> 2) & 1, pp = tid & 3;
                float acc = 0.f;
                int k0 = pp * 32;
                for (int k = k0; k < k0 + 32; ++k)
                    acc += hbuf[i * 128 + (k ^ ((i & 7) << 2))] * WoutL[k * 2 + d];
                red[tid] = acc;
            }
            __syncthreads();
            if (tid < 64) {
                int d = tid & 1;
                float pv = red[tid * 4] + red[tid * 4 + 1] + red[tid * 4 + 2] + red[tid * 4 + 3]
                         + boutL[d];
                out[(t - OBS_T) * 2048 + b * 64 + tid] = pv;
                posb[tid] += pv;
                pvbuf[tid] = pv;
            }
            __syncthreads();
            {
                int e0 = gg * 4;
                float x0 = pvbuf[gi * 2], x1 = pvbuf[gi * 2 + 1];
#pragma unroll
                for (int r = 0; r < 4; ++r) {
                    int e = e0 + r;
                    float v = x0 * WeL[e] + x1 * WeL[64 + e] + beL[e];
                    store2(combH, combM, gi * 256 + (e ^ ((gi & 7) << 3)), v);
                }
            }
        }
        __syncthreads();

        // ---------- G: gate preactivations (bf16x2 MFMA, ks-prefetched) ----------
        {
            f32x4 acc[4][2];
            f32x4 zero = {0.f, 0.f, 0.f, 0.f};
#pragma unroll
            for (int q = 0; q < 4; ++q) { acc[q][0] = zero; acc[q][1] = zero; }
            s8v bh[2][4], bl[2][4];
#pragma unroll
            for (int q = 0; q < 4; ++q) {
                int fo = ((wv * 4 + q) * 8 + 0) * 64 + lane;
                bh[0][q] = ((const s8v*)W4H)[fo];
                bl[0][q] = ((const s8v*)W4L)[fo];
            }
#pragma unroll
            for (int ks = 0; ks < 8; ++ks) {
                const int cb = ks & 1;
                if (ks < 7) {   // prefetch next ks's 8 frags
#pragma unroll
                    for (int q = 0; q < 4; ++q) {
                        int fo = ((wv * 4 + q) * 8 + ks + 1) * 64 + lane;
                        bh[cb ^ 1][q] = ((const s8v*)W4H)[fo];
                        bl[cb ^ 1][q] = ((const s8v*)W4L)[fo];
                    }
                }
                s8v Ah[2], Am[2];
#pragma unroll
                for (int m = 0; m < 2; ++m) {
                    int row = m * 16 + (lane & 15);
                    int k = ks * 32 + ((lane >> 4) << 3);
                    int ci = row * 256 + (k ^ ((row & 7) << 3));
                    Ah[m] = *(const s8v*)&combH[ci];
                    Am[m] = *(const s8v*)&combM[ci];
                }
#pragma unroll
                for (int q = 0; q < 4; ++q)
#pragma unroll
                    for (int m = 0; m < 2; ++m) {
                        acc[q][m] = __builtin_amdgcn_mfma_f32_16x16x32_bf16(Am[m], bh[cb][q], acc[q][m], 0, 0, 0);
                        acc[q][m] = __builtin_amdgcn_mfma_f32_16x16x32_bf16(Ah[m], bl[cb][q], acc[q][m], 0, 0, 0);
                        acc[q][m] = __builtin_amdgcn_mfma_f32_16x16x32_bf16(Ah[m], bh[cb][q], acc[q][m], 0, 0, 0);
                    }
            }
#pragma unroll
            for (int q = 0; q < 4; ++q) {
                int nt = wv * 4 + q;
                int n = nt * 16 + (lane & 15);
#pragma unroll
                for (int m = 0; m < 2; ++m)
#pragma unroll
                    for (int r = 0; r < 4; ++r) {
                        int i = m * 16 + ((lane >> 4) << 2) + r;
                        scratch[i * 512 + (n ^ (((i >> 2) & 3) << 4))] = acc[q][m][r];
                    }
            }
        }
        __syncthreads();

        // ---------- C: LSTM cell (elementwise, f32) ----------
        {
            int k0 = gg * 8;
            float hv[8];
#pragma unroll
            for (int r = 0; r < 8; ++r) {
                int k = k0 + r;
                int sw = ((gi >> 2) & 3) << 4;
                float pi = scratch[gi * 512 + ((      k) ^ sw)] + biasL[k];
                float pf = scratch[gi * 512 + ((128 + k) ^ sw)] + biasL[128 + k];
                float po = scratch[gi * 512 + ((256 + k) ^ sw)] + biasL[256 + k];
                float pg = scratch[gi * 512 + ((384 + k) ^ sw)] + biasL[384 + k];
                float ig = 1.f / (1.f + expf(-pi));
                float fg = 1.f / (1.f + expf(-pf));
                float og = 1.f / (1.f + expf(-po));
                float gv = tanhf(pg);
                float cv = fg * creg[r] + ig * gv;
                creg[r] = cv;
                hv[r] = og * tanhf(cv);
            }
#pragma unroll
            for (int r = 0; r < 8; ++r) {
                int k = k0 + r;
                hbuf[gi * 128 + (k ^ ((gi & 7) << 2))] = hv[r];
                store2(combH, combM, gi * 256 + ((64 + k) ^ ((gi & 7) << 3)), hv[r]);
            }
        }
        __syncthreads();
    }
}

extern "C" void kernel_launch(void* const* d_in, const int* in_sizes, int n_in,
                              void* d_out, int out_size, void* d_ws, size_t ws_size,
                              hipStream_t stream) {
    const float* obs_rel = (const float*)d_in[0];
    const float* obs_abs = (const float*)d_in[1];
    // d_in[2]: seq_start_end — fixed contiguous blocks of 32, unused
    const float* We   = (const float*)d_in[3];
    const float* be   = (const float*)d_in[4];
    const float* Wp   = (const float*)d_in[5];
    const float* bp   = (const float*)d_in[6];
    const float* Wi   = (const float*)d_in[7];
    const float* bi   = (const float*)d_in[8];
    const float* Wf   = (const float*)d_in[9];
    const float* bf   = (const float*)d_in[10];
    const float* Wo   = (const float*)d_in[11];
    const float* bo   = (const float*)d_in[12];
    const float* Wg   = (const float*)d_in[13];
    const float* bg   = (const float*)d_in[14];
    const float* Wout = (const float*)d_in[15];
    const float* bout = (const float*)d_in[16];

    unsigned short* ws = (unsigned short*)d_ws;
    unsigned short* W4H = ws;
    unsigned short* W4L = W4H + 131072;
    unsigned short* WpH = W4L + 131072;
    unsigned short* WpL = WpH + 524288;

    slstm_prep<<<2560, 256, 0, stream>>>(Wp, Wi, Wf, Wo, Wg, W4H, W4L, WpH, WpL);
    slstm_main<<<32, 512, 0, stream>>>(obs_rel, obs_abs, We, be, bp, bi, bf, bo, bg,
                                       Wout, bout, W4H, W4L, WpH, WpL,
                                       (float*)d_out);
}

// Round 7
// 1201.356 us; speedup vs baseline: 2.2313x; 1.1800x over previous
//
#include <hip/hip_runtime.h>

typedef short s8v __attribute__((ext_vector_type(8)));
typedef float f32x4 __attribute__((ext_vector_type(4)));

#define OBS_T 8
#define NSTEPS 20

__device__ __forceinline__ unsigned short f2bf(float x) {
    unsigned u = __float_as_uint(x);
    u = (u + 0x7FFFu + ((u >> 16) & 1u)) >> 16;
    return (unsigned short)u;
}
__device__ __forceinline__ float bf2f(unsigned short h) {
    return __uint_as_float(((unsigned)h) << 16);
}

__device__ __forceinline__ void store2(unsigned short* H, unsigned short* M,
                                       int ci, float v) {
    unsigned short h = f2bf(v);
    H[ci] = h; M[ci] = f2bf(v - bf2f(h));
}

// ---------------- prep: pack x2-split bf16 weight fragments ----------------
// W4frag (x2): [nt2(32)][ks(8)][lane(64)][j(8)]
//   nt2 = wv*4+q : gate q in {i,f,o,g}, hcol block wv*16..+15
//   n = q*128 + wv*16 + (lane&15), k = ks*32+(lane>>4)*8+j
// Wpfrag (x2): [bin(64)][nt(4)][ks(4)][lane(64)][j(8)] e=nt*16+(l&15), k=ks*32+(l>>4)*8+j
__global__ void slstm_prep(const float* __restrict__ Wp,
                           const float* __restrict__ Wi, const float* __restrict__ Wf,
                           const float* __restrict__ Wo, const float* __restrict__ Wg,
                           unsigned short* __restrict__ W4H, unsigned short* __restrict__ W4L,
                           unsigned short* __restrict__ WpH, unsigned short* __restrict__ WpL) {
    int x = blockIdx.x * blockDim.x + threadIdx.x;
    const int NW4 = 32 * 8 * 64 * 8;      // 131072
    const int NWP = 64 * 4 * 4 * 64 * 8;  // 524288
    if (x < NW4) {
        int j = x & 7, lane = (x >> 3) & 63, ks = (x >> 9) & 7, nt2 = x >> 12;
        int q = nt2 & 3, wvb = nt2 >> 2;
        int col = wvb * 16 + (lane & 15);
        int k = ks * 32 + ((lane >> 4) << 3) + j;
        const float* W = (q == 0) ? Wi : (q == 1) ? Wf : (q == 2) ? Wo : Wg;
        float v = W[k * 128 + col];
        unsigned short h = f2bf(v);
        W4H[x] = h; W4L[x] = f2bf(v - bf2f(h));
    } else if (x < NW4 + NWP) {
        int y = x - NW4;
        int j = y & 7, lane = (y >> 3) & 63, ks = (y >> 9) & 3, nt = (y >> 11) & 3, bin = y >> 13;
        int e = nt * 16 + (lane & 15);
        int k = ks * 32 + ((lane >> 4) << 3) + j;
        float v = Wp[(bin * 128 + k) * 64 + e];
        unsigned short h = f2bf(v);
        WpH[y] = h; WpL[y] = f2bf(v - bf2f(h));
    }
}

// ---------------- main persistent kernel: 1 WG per sequence ----------------
__global__ __launch_bounds__(512, 1) void slstm_main(
    const float* __restrict__ obs_rel, const float* __restrict__ obs_abs,
    const float* __restrict__ We, const float* __restrict__ be,
    const float* __restrict__ bp,
    const float* __restrict__ bi, const float* __restrict__ bfv,
    const float* __restrict__ bo, const float* __restrict__ bg,
    const float* __restrict__ Wout, const float* __restrict__ bout,
    const unsigned short* __restrict__ W4H, const unsigned short* __restrict__ W4L,
    const unsigned short* __restrict__ WpH, const unsigned short* __restrict__ WpL,
    float* __restrict__ out) {

    __shared__ __align__(16) unsigned short combH[32 * 256];  // [emb|h|s] hi
    __shared__ __align__(16) unsigned short combM[32 * 256];  // lo (x2 split)
    __shared__ __align__(16) float hbuf[32 * 128];            // f32 h (for pv)
    __shared__ __align__(16) float scratch[32 * 512];         // Y chunk staging (64KB)
    __shared__ float posb[64];
    __shared__ float pvbuf[64];
    __shared__ float red[256];
    __shared__ unsigned char binTab[1024];
    __shared__ unsigned char usedList[64];
    __shared__ unsigned char binSlotG[64];
    __shared__ unsigned short glist[1024];                    // per-i pair list, chunk-sorted
    __shared__ unsigned long long gstartPacked[32];           // 8 x 5-bit prefix per i
    __shared__ int nUsedS;
    __shared__ unsigned usedMask[2];
    __shared__ unsigned jm[4];   // [0..1]: bins with some j<16; [2..3]: some j>=16
    __shared__ float biasL[512], beL[64], bpL[64], WeL[128], WoutL[256], boutL[2];

    const int tid = threadIdx.x;
    const int lane = tid & 63;
    const int wv = tid >> 6;
    const int b = blockIdx.x;

    if (tid < 512) biasL[tid] = (tid < 128) ? bi[tid] : (tid < 256) ? bfv[tid - 128]
                              : (tid < 384) ? bo[tid - 256] : bg[tid - 384];
    if (tid < 64) { beL[tid] = be[tid]; bpL[tid] = bp[tid]; }
    if (tid < 128) WeL[tid] = We[tid];
    if (tid < 256) WoutL[tid] = Wout[tid];
    if (tid < 2) boutL[tid] = bout[tid];
    for (int x = tid; x < 32 * 256; x += 512) { combH[x] = 0; combM[x] = 0; }
    for (int x = tid; x < 32 * 128; x += 512) hbuf[x] = 0.f;
    // cell state: lane owns rows {m*16+(lane>>4)*4+r} at hcol hc = wv*16+(lane&15)
    float creg[8];
#pragma unroll
    for (int r = 0; r < 8; ++r) creg[r] = 0.f;
    __syncthreads();

    const float gnorm = (float)(2.0 / 7.0);
    const int gi = tid >> 4;
    const int gg = tid & 15;
    const int hc = wv * 16 + (lane & 15);   // gate/cell hcol owned by this lane

    for (int t = 0; t < NSTEPS; ++t) {
        // ---------- E_obs: positions + embedding ----------
        if (t < OBS_T) {
            if (tid < 64) posb[tid] = obs_abs[t * 2048 + b * 64 + tid];
            {
                int e0 = gg * 4;
                float x0 = obs_rel[t * 2048 + b * 64 + gi * 2];
                float x1 = obs_rel[t * 2048 + b * 64 + gi * 2 + 1];
#pragma unroll
                for (int r = 0; r < 4; ++r) {
                    int e = e0 + r;
                    float v = x0 * WeL[e] + x1 * WeL[64 + e] + beL[e];
                    store2(combH, combM, gi * 256 + (e ^ ((gi & 7) << 3)), v);
                }
            }
        }
        if (tid < 2) usedMask[tid] = 0u;
        if (tid < 4) jm[tid] = 0u;
        __syncthreads();

        // ---------- S: social pooling ----------
        float sreg[4] = {0.f, 0.f, 0.f, 0.f};
        if (t > 0) {
            // S0: bins for all pairs
#pragma unroll
            for (int pp = 0; pp < 2; ++pp) {
                int p = tid + pp * 512;
                int i = p >> 5, j = p & 31;
                float rx = (posb[j * 2]     - posb[i * 2])     / gnorm;
                float ry = (posb[j * 2 + 1] - posb[i * 2 + 1]) / gnorm;
                rx = fminf(fmaxf(rx, -4.f), 4.f);
                ry = fminf(fmaxf(ry, -4.f), 4.f);
                int gx = (int)(rx + 4.f);
                int gy = (int)(ry + 4.f);
                int valid = (gx < 8) && (gy < 8) && (i != j);
                int bin = gy * 8 + gx;
                binTab[p] = valid ? (unsigned char)bin : (unsigned char)255;
                if (valid) {
                    atomicOr(&usedMask[bin >> 5], 1u << (bin & 31));
                    atomicOr(&jm[((j < 16) ? 0 : 2) + (bin >> 5)], 1u << (bin & 31));
                }
            }
            __syncthreads();
            // S1: compact used-bin list — wave-parallel ballot prefix (lane = bin)
            if (wv == 0) {
                bool used = (usedMask[lane >> 5] >> (lane & 31)) & 1u;
                unsigned long long bal = __ballot(used);
                int myIdx = __popcll(bal & ((1ull << lane) - 1ull));
                if (used) { usedList[myIdx] = (unsigned char)lane; }
                binSlotG[lane] = used ? (unsigned char)myIdx : (unsigned char)255;
                if (lane == 0) nUsedS = __popcll(bal);
            }
            __syncthreads();
            const int nUsed = nUsedS;
            const int nChunks = (nUsed + 7) >> 3;

            // A-frags: h rows (comb cols 64..191), x2 split, held in regs
            s8v Ah[2][4], Am[2][4];
#pragma unroll
            for (int m = 0; m < 2; ++m)
#pragma unroll
                for (int ks = 0; ks < 4; ++ks) {
                    int row = m * 16 + (lane & 15);
                    int k = ks * 32 + ((lane >> 4) << 3);
                    int ci = row * 256 + ((64 + k) ^ ((row & 7) << 3));
                    Ah[m][ks] = *(const s8v*)&combH[ci];
                    Am[m][ks] = *(const s8v*)&combM[ci];
                }

            // build per-(i,chunk) gather lists (tid<32), overlapped with chunk 0 MFMA
            if (tid < 32) {
                const int i = tid;
                unsigned rw[8];
#pragma unroll
                for (int w = 0; w < 8; ++w)
                    rw[w] = *(const unsigned*)&binTab[i * 32 + w * 4];
                unsigned long long cntp = 0;
#pragma unroll
                for (int j = 0; j < 32; ++j) {
                    unsigned bb = (rw[j >> 2] >> ((j & 3) * 8)) & 255u;
                    if (bb != 255u) {
                        int c = binSlotG[bb] >> 3;
                        cntp += 1ull << (5 * c);
                    }
                }
                unsigned long long pre = 0; unsigned sum = 0;
#pragma unroll
                for (int c = 0; c < 8; ++c) {
                    pre |= (unsigned long long)sum << (5 * c);
                    sum += (unsigned)((cntp >> (5 * c)) & 31);
                }
                gstartPacked[i] = pre | ((unsigned long long)sum << 40);
                unsigned long long pos = pre;
#pragma unroll
                for (int j = 0; j < 32; ++j) {
                    unsigned bb = (rw[j >> 2] >> ((j & 3) * 8)) & 255u;
                    if (bb != 255u) {
                        int sg = binSlotG[bb];
                        int c = sg >> 3;
                        int p = (int)((pos >> (5 * c)) & 31);
                        glist[i * 32 + p] = (unsigned short)((sg << 5) | j);
                        pos += 1ull << (5 * c);
                    }
                }
            }

            unsigned long long spReg = 0;
            for (int c = 0; c < nChunks; ++c) {
                int idx = c * 8 + wv;
                if (idx < nUsed) {
                    int bin = usedList[idx];
                    const bool do0 = (jm[bin >> 5]       >> (bin & 31)) & 1;
                    const bool do1 = (jm[2 + (bin >> 5)] >> (bin & 31)) & 1;
                    s8v bh[2][4], bl[2][4];
#pragma unroll
                    for (int ks = 0; ks < 4; ++ks) {
                        int fo = ((bin * 4 + 0) * 4 + ks) * 64 + lane;
                        bh[0][ks] = ((const s8v*)WpH)[fo];
                        bl[0][ks] = ((const s8v*)WpL)[fo];
                    }
#pragma unroll
                    for (int nt = 0; nt < 4; ++nt) {
                        const int cb = nt & 1;
                        if (nt < 3) {   // prefetch next nt's frags into other buffer
#pragma unroll
                            for (int ks = 0; ks < 4; ++ks) {
                                int fo = ((bin * 4 + nt + 1) * 4 + ks) * 64 + lane;
                                bh[cb ^ 1][ks] = ((const s8v*)WpH)[fo];
                                bl[cb ^ 1][ks] = ((const s8v*)WpL)[fo];
                            }
                        }
                        f32x4 a0 = {0.f, 0.f, 0.f, 0.f};
                        f32x4 a1 = {0.f, 0.f, 0.f, 0.f};
                        if (do0) {
#pragma unroll
                            for (int ks = 0; ks < 4; ++ks) {
                                a0 = __builtin_amdgcn_mfma_f32_16x16x32_bf16(Am[0][ks], bh[cb][ks], a0, 0, 0, 0);
                                a0 = __builtin_amdgcn_mfma_f32_16x16x32_bf16(Ah[0][ks], bl[cb][ks], a0, 0, 0, 0);
                                a0 = __builtin_amdgcn_mfma_f32_16x16x32_bf16(Ah[0][ks], bh[cb][ks], a0, 0, 0, 0);
                            }
                        }
                        if (do1) {
#pragma unroll
                            for (int ks = 0; ks < 4; ++ks) {
                                a1 = __builtin_amdgcn_mfma_f32_16x16x32_bf16(Am[1][ks], bh[cb][ks], a1, 0, 0, 0);
                                a1 = __builtin_amdgcn_mfma_f32_16x16x32_bf16(Ah[1][ks], bl[cb][ks], a1, 0, 0, 0);
                                a1 = __builtin_amdgcn_mfma_f32_16x16x32_bf16(Ah[1][ks], bh[cb][ks], a1, 0, 0, 0);
                            }
                        }
                        int e = nt * 16 + (lane & 15);
                        if (do0) {
#pragma unroll
                            for (int r = 0; r < 4; ++r) {
                                int j0 = ((lane >> 4) << 2) + r;
                                scratch[j0 * 512 + wv * 64 + (e ^ (((j0 >> 2) & 3) << 4))] = a0[r];
                            }
                        }
                        if (do1) {
#pragma unroll
                            for (int r = 0; r < 4; ++r) {
                                int j1 = 16 + ((lane >> 4) << 2) + r;
                                scratch[j1 * 512 + wv * 64 + (e ^ (((j1 >> 2) & 3) << 4))] = a1[r];
                            }
                        }
                    }
                }
                __syncthreads();
                // gather via per-(i,chunk) lists
                {
                    const int e0 = gg * 4;
                    if (c == 0) spReg = gstartPacked[gi];
                    int p0 = (int)((spReg >> (5 * c)) & 31);
                    int p1 = (int)((spReg >> (5 * c + 5)) & 31);
                    for (int p = p0; p < p1; ++p) {
                        unsigned en = glist[gi * 32 + p];
                        int slot = (en >> 5) & 7;
                        int j = en & 31;
                        const float4 y = *(const float4*)
                            &scratch[j * 512 + slot * 64 + (e0 ^ (((j >> 2) & 3) << 4))];
                        sreg[0] += y.x; sreg[1] += y.y; sreg[2] += y.z; sreg[3] += y.w;
                    }
                }
                __syncthreads();
            }
        }

        // gates B-frag ks=0 prefetch (hoisted: independent of comb/s)
        s8v gbh[2][4], gbl[2][4];
#pragma unroll
        for (int q = 0; q < 4; ++q) {
            int fo = ((wv * 4 + q) * 8 + 0) * 64 + lane;
            gbh[0][q] = ((const s8v*)W4H)[fo];
            gbl[0][q] = ((const s8v*)W4L)[fo];
        }

        // finalize s = relu(pooled + bp) -> comb cols 192..255
        {
            int e0 = gg * 4;
#pragma unroll
            for (int r = 0; r < 4; ++r) {
                float v = fmaxf(sreg[r] + bpL[e0 + r], 0.f);
                store2(combH, combM, gi * 256 + ((192 + e0 + r) ^ ((gi & 7) << 3)), v);
            }
        }

        // ---------- E_pred: pv, output, pos update, embedding ----------
        if (t >= OBS_T) {
            if (tid < 256) {
                int i = tid >> 3, d = (tid >> 2) & 1, pp = tid & 3;
                float acc = 0.f;
                int k0 = pp * 32;
                for (int k = k0; k < k0 + 32; ++k)
                    acc += hbuf[i * 128 + (k ^ ((i & 7) << 2))] * WoutL[k * 2 + d];
                red[tid] = acc;
            }
            __syncthreads();
            if (tid < 64) {
                int d = tid & 1;
                float pv = red[tid * 4] + red[tid * 4 + 1] + red[tid * 4 + 2] + red[tid * 4 + 3]
                         + boutL[d];
                out[(t - OBS_T) * 2048 + b * 64 + tid] = pv;
                posb[tid] += pv;
                pvbuf[tid] = pv;
            }
            __syncthreads();
            {
                int e0 = gg * 4;
                float x0 = pvbuf[gi * 2], x1 = pvbuf[gi * 2 + 1];
#pragma unroll
                for (int r = 0; r < 4; ++r) {
                    int e = e0 + r;
                    float v = x0 * WeL[e] + x1 * WeL[64 + e] + beL[e];
                    store2(combH, combM, gi * 256 + (e ^ ((gi & 7) << 3)), v);
                }
            }
        }
        __syncthreads();

        // ---------- G+C: gate preactivations (bf16x2 MFMA) + in-register cell ----------
        {
            f32x4 acc[4][2];
            f32x4 zero = {0.f, 0.f, 0.f, 0.f};
#pragma unroll
            for (int q = 0; q < 4; ++q) { acc[q][0] = zero; acc[q][1] = zero; }
#pragma unroll
            for (int ks = 0; ks < 8; ++ks) {
                const int cb = ks & 1;
                if (ks < 7) {   // prefetch next ks's 8 frags
#pragma unroll
                    for (int q = 0; q < 4; ++q) {
                        int fo = ((wv * 4 + q) * 8 + ks + 1) * 64 + lane;
                        gbh[cb ^ 1][q] = ((const s8v*)W4H)[fo];
                        gbl[cb ^ 1][q] = ((const s8v*)W4L)[fo];
                    }
                }
                s8v Ah[2], Am[2];
#pragma unroll
                for (int m = 0; m < 2; ++m) {
                    int row = m * 16 + (lane & 15);
                    int k = ks * 32 + ((lane >> 4) << 3);
                    int ci = row * 256 + (k ^ ((row & 7) << 3));
                    Ah[m] = *(const s8v*)&combH[ci];
                    Am[m] = *(const s8v*)&combM[ci];
                }
#pragma unroll
                for (int q = 0; q < 4; ++q)
#pragma unroll
                    for (int m = 0; m < 2; ++m) {
                        acc[q][m] = __builtin_amdgcn_mfma_f32_16x16x32_bf16(Am[m], gbh[cb][q], acc[q][m], 0, 0, 0);
                        acc[q][m] = __builtin_amdgcn_mfma_f32_16x16x32_bf16(Ah[m], gbl[cb][q], acc[q][m], 0, 0, 0);
                        acc[q][m] = __builtin_amdgcn_mfma_f32_16x16x32_bf16(Ah[m], gbh[cb][q], acc[q][m], 0, 0, 0);
                    }
            }
            __syncthreads();  // all waves done reading comb (A-frags) before h writes

            // in-register LSTM cell: lane owns 8 (row, hc) pairs
            float b0 = biasL[hc], b1 = biasL[128 + hc], b2 = biasL[256 + hc], b3 = biasL[384 + hc];
#pragma unroll
            for (int m = 0; m < 2; ++m)
#pragma unroll
                for (int r = 0; r < 4; ++r) {
                    int s = m * 4 + r;
                    int row = m * 16 + ((lane >> 4) << 2) + r;
                    float pi = acc[0][m][r] + b0;
                    float pf = acc[1][m][r] + b1;
                    float po = acc[2][m][r] + b2;
                    float pg = acc[3][m][r] + b3;
                    float ig = 1.f / (1.f + expf(-pi));
                    float fg = 1.f / (1.f + expf(-pf));
                    float og = 1.f / (1.f + expf(-po));
                    float gv = tanhf(pg);
                    float cv = fg * creg[s] + ig * gv;
                    creg[s] = cv;
                    float hv = og * tanhf(cv);
                    hbuf[row * 128 + (hc ^ ((row & 7) << 2))] = hv;
                    store2(combH, combM, row * 256 + ((64 + hc) ^ ((row & 7) << 3)), hv);
                }
        }
        __syncthreads();
    }
}

extern "C" void kernel_launch(void* const* d_in, const int* in_sizes, int n_in,
                              void* d_out, int out_size, void* d_ws, size_t ws_size,
                              hipStream_t stream) {
    const float* obs_rel = (const float*)d_in[0];
    const float* obs_abs = (const float*)d_in[1];
    // d_in[2]: seq_start_end — fixed contiguous blocks of 32, unused
    const float* We   = (const float*)d_in[3];
    const float* be   = (const float*)d_in[4];
    const float* Wp   = (const float*)d_in[5];
    const float* bp   = (const float*)d_in[6];
    const float* Wi   = (const float*)d_in[7];
    const float* bi   = (const float*)d_in[8];
    const float* Wf   = (const float*)d_in[9];
    const float* bf   = (const float*)d_in[10];
    const float* Wo   = (const float*)d_in[11];
    const float* bo   = (const float*)d_in[12];
    const float* Wg   = (const float*)d_in[13];
    const float* bg   = (const float*)d_in[14];
    const float* Wout = (const float*)d_in[15];
    const float* bout = (const float*)d_in[16];

    unsigned short* ws = (unsigned short*)d_ws;
    unsigned short* W4H = ws;
    unsigned short* W4L = W4H + 131072;
    unsigned short* WpH = W4L + 131072;
    unsigned short* WpL = WpH + 524288;

    slstm_prep<<<2560, 256, 0, stream>>>(Wp, Wi, Wf, Wo, Wg, W4H, W4L, WpH, WpL);
    slstm_main<<<32, 512, 0, stream>>>(obs_rel, obs_abs, We, be, bp, bi, bf, bo, bg,
                                       Wout, bout, W4H, W4L, WpH, WpL,
                                       (float*)d_out);
}